// Round 1
// baseline (566.292 us; speedup 1.0000x reference)
//
#include <hip/hip_runtime.h>
#include <stdint.h>

#define P_TOT   4096      // B*H*W
#define N_CODE  16384
#define DIM     256
#define HW      1024
#define CHW     262144
#define MT      128
#define NT      128
#define KB      32
#define S       36        // LDS row stride (words); 36*4B=144B, 16B aligned, odd-mod-32-ish banks
#define NBLK    128       // 16384 / NT

typedef unsigned long long u64;

__device__ __forceinline__ unsigned int mono(float f) {
  unsigned int u = __float_as_uint(f);
  return (u & 0x80000000u) ? ~u : (u | 0x80000000u);
}

// ---- codebook squared norms: one wave per code ----
__global__ __launch_bounds__(256) void k_cnorm(const float* __restrict__ cb,
                                               float* __restrict__ cnorm) {
  int code = blockIdx.x * 4 + (threadIdx.x >> 6);
  int lane = threadIdx.x & 63;
  float4 v = ((const float4*)(cb + (size_t)code * DIM))[lane];
  float s = fmaf(v.x, v.x, fmaf(v.y, v.y, fmaf(v.z, v.z, v.w * v.w)));
  #pragma unroll
  for (int off = 32; off; off >>= 1) s += __shfl_down(s, off, 64);
  if (lane == 0) cnorm[code] = s;
}

// ---- transpose dec_w [3][256][3][3] -> [oc][ky][kx][256] ----
__global__ __launch_bounds__(256) void k_wt(const float* __restrict__ w,
                                            float* __restrict__ wt) {
  int e = blockIdx.x * 256 + threadIdx.x;   // 6912 total
  int ic = e & 255;
  int r = e >> 8;
  int kx = r % 3; r /= 3;
  int ky = r % 3;
  int oc = r / 3;
  wt[e] = w[((oc * 256 + ic) * 3 + ky) * 3 + kx];
}

// ---- main VQ: fp32 register-tiled distance + per-(row,nblock) argmin partial ----
__global__ __launch_bounds__(256) void k_vq(const float* __restrict__ latent,
                                            const float* __restrict__ cb,
                                            const float* __restrict__ cnorm,
                                            u64* __restrict__ partial) {
  __shared__ __align__(16) float xs[MT * S];
  __shared__ __align__(16) float cs[NT * S];
  __shared__ float cn[NT];
  int nb = blockIdx.x, mb = blockIdx.y;
  int t = threadIdx.x;
  int tx = t & 15, ty = t >> 4;

  int bidx = mb >> 3;                 // batch index (8 m-blocks per batch)
  int hw0 = (mb & 7) * MT;
  const float* Xb = latent + (size_t)bidx * CHW + hw0;   // x(r,c) = Xb[c*HW + r]
  const float* Cb = cb + (size_t)nb * NT * DIM;

  if (t < NT) cn[t] = cnorm[nb * NT + t];

  float acc[8][8];
  #pragma unroll
  for (int i = 0; i < 8; i++)
    #pragma unroll
    for (int j = 0; j < 8; j++) acc[i][j] = 0.0f;

  int lp = t & 127, cg = t >> 7;      // x-tile loader mapping
  int code = t >> 1, half = t & 1;    // c-tile loader mapping

  for (int kb = 0; kb < DIM; kb += KB) {
    __syncthreads();
    #pragma unroll
    for (int ci = 0; ci < 16; ci++) {
      int cl = cg * 16 + ci;
      xs[lp * S + cl] = Xb[(size_t)(kb + cl) * HW + lp];
    }
    #pragma unroll
    for (int q = 0; q < 4; q++) {
      int kk = half * 16 + q * 4;
      float4 v = *(const float4*)(Cb + (size_t)code * DIM + kb + kk);
      *(float4*)&cs[code * S + kk] = v;
    }
    __syncthreads();
    #pragma unroll
    for (int kk = 0; kk < KB; kk += 4) {
      float4 xv[8], cv[8];
      #pragma unroll
      for (int i = 0; i < 8; i++) xv[i] = *(const float4*)&xs[(ty + 16 * i) * S + kk];
      #pragma unroll
      for (int j = 0; j < 8; j++) cv[j] = *(const float4*)&cs[(tx + 16 * j) * S + kk];
      #pragma unroll
      for (int i = 0; i < 8; i++)
        #pragma unroll
        for (int j = 0; j < 8; j++) {
          float a = acc[i][j];
          a = fmaf(xv[i].x, cv[j].x, a);
          a = fmaf(xv[i].y, cv[j].y, a);
          a = fmaf(xv[i].z, cv[j].z, a);
          a = fmaf(xv[i].w, cv[j].w, a);
          acc[i][j] = a;
        }
    }
  }

  __syncthreads();
  u64* red = (u64*)cs;   // 128 rows * 16 tx * 8B = 16 KB <= sizeof(cs)
  #pragma unroll
  for (int i = 0; i < 8; i++) {
    u64 best = 0xFFFFFFFFFFFFFFFFull;
    #pragma unroll
    for (int j = 0; j < 8; j++) {
      int cj = tx + 16 * j;
      float val = fmaf(-2.0f, acc[i][j], cn[cj]);   // ||c||^2 - 2 x.c  (row const dropped)
      u64 key = ((u64)mono(val) << 32) | (unsigned)(nb * NT + cj);
      best = key < best ? key : best;
    }
    red[(ty + 16 * i) * 16 + tx] = best;
  }
  __syncthreads();
  if (t < MT) {
    u64 m = 0xFFFFFFFFFFFFFFFFull;
    #pragma unroll
    for (int k = 0; k < 16; k++) {
      u64 v = red[t * 16 + k];
      m = v < m ? v : m;
    }
    partial[(size_t)(mb * MT + t) * NBLK + nb] = m;
  }
}

// ---- per-row top-2 reduce + exact fp64 refinement -> final index ----
__global__ __launch_bounds__(128) void k_reduce(const u64* __restrict__ partial,
                                                const float* __restrict__ latent,
                                                const float* __restrict__ cb,
                                                int* __restrict__ idxo) {
  int p = blockIdx.x;
  int t = threadIdx.x;
  __shared__ u64 s[128];
  u64 v = partial[(size_t)p * NBLK + t];
  s[t] = v; __syncthreads();
  #pragma unroll
  for (int off = 64; off; off >>= 1) {
    if (t < off) { u64 o = s[t + off]; if (o < s[t]) s[t] = o; }
    __syncthreads();
  }
  u64 m1 = s[0]; __syncthreads();
  s[t] = (v == m1) ? 0xFFFFFFFFFFFFFFFFull : v; __syncthreads();
  #pragma unroll
  for (int off = 64; off; off >>= 1) {
    if (t < off) { u64 o = s[t + off]; if (o < s[t]) s[t] = o; }
    __syncthreads();
  }
  u64 m2 = s[0];
  int n1 = (int)(m1 & 0xFFFFFFFFull);
  int n2 = (int)(m2 & 0xFFFFFFFFull);

  int b = p >> 10, hw = p & 1023;
  const float* xb = latent + (size_t)b * CHW + hw;
  double d1 = 0.0, d2 = 0.0;
  for (int c = t; c < DIM; c += 128) {
    double xv = (double)xb[(size_t)c * HW];
    double e1 = xv - (double)cb[(size_t)n1 * DIM + c]; d1 += e1 * e1;
    double e2 = xv - (double)cb[(size_t)n2 * DIM + c]; d2 += e2 * e2;
  }
  __shared__ double r1[128], r2[128];
  r1[t] = d1; r2[t] = d2; __syncthreads();
  #pragma unroll
  for (int off = 64; off; off >>= 1) {
    if (t < off) { r1[t] += r1[t + off]; r2[t] += r2[t + off]; }
    __syncthreads();
  }
  if (t == 0) {
    int best = (r2[0] < r1[0] || (r2[0] == r1[0] && n2 < n1)) ? n2 : n1;
    idxo[p] = best;
  }
}

// ---- gather + 3x3 conv + bias + (x+1)*0.5 + clamp ----
__global__ __launch_bounds__(256) void k_conv(const float* __restrict__ cb,
                                              const int* __restrict__ idx,
                                              const float* __restrict__ wt,
                                              const float* __restrict__ bias,
                                              float* __restrict__ out) {
  int y = blockIdx.x, b = blockIdx.y;
  int t = threadIdx.x;
  int x = t & 31, icg = t >> 5;     // 8 ic-groups of 32 channels
  float a0 = 0.f, a1 = 0.f, a2 = 0.f;
  #pragma unroll
  for (int dy = -1; dy <= 1; dy++) {
    int yy = y + dy;
    if (yy < 0 || yy >= 32) continue;
    #pragma unroll
    for (int dx = -1; dx <= 1; dx++) {
      int xx = x + dx;
      if (xx < 0 || xx >= 32) continue;
      int n = idx[b * HW + yy * 32 + xx];
      const float4* crow = (const float4*)(cb + (size_t)n * DIM + icg * 32);
      int tap = (dy + 1) * 3 + (dx + 1);
      const float4* w0 = (const float4*)(wt + (size_t)(0 * 9 + tap) * DIM + icg * 32);
      const float4* w1 = (const float4*)(wt + (size_t)(1 * 9 + tap) * DIM + icg * 32);
      const float4* w2 = (const float4*)(wt + (size_t)(2 * 9 + tap) * DIM + icg * 32);
      #pragma unroll
      for (int q = 0; q < 8; q++) {
        float4 qv = crow[q];
        float4 wa = w0[q];
        a0 = fmaf(qv.x, wa.x, a0); a0 = fmaf(qv.y, wa.y, a0);
        a0 = fmaf(qv.z, wa.z, a0); a0 = fmaf(qv.w, wa.w, a0);
        float4 wb = w1[q];
        a1 = fmaf(qv.x, wb.x, a1); a1 = fmaf(qv.y, wb.y, a1);
        a1 = fmaf(qv.z, wb.z, a1); a1 = fmaf(qv.w, wb.w, a1);
        float4 wc = w2[q];
        a2 = fmaf(qv.x, wc.x, a2); a2 = fmaf(qv.y, wc.y, a2);
        a2 = fmaf(qv.z, wc.z, a2); a2 = fmaf(qv.w, wc.w, a2);
      }
    }
  }
  __shared__ float red[3][32][8];
  red[0][x][icg] = a0; red[1][x][icg] = a1; red[2][x][icg] = a2;
  __syncthreads();
  if (t < 96) {
    int oc = t >> 5, xo = t & 31;
    float sum = 0.f;
    #pragma unroll
    for (int k = 0; k < 8; k++) sum += red[oc][xo][k];
    sum += bias[oc];
    sum = (sum + 1.0f) * 0.5f;
    sum = fminf(fmaxf(sum, 0.0f), 1.0f);
    out[((size_t)(b * 3 + oc) * 32 + y) * 32 + xo] = sum;
  }
}

extern "C" void kernel_launch(void* const* d_in, const int* in_sizes, int n_in,
                              void* d_out, int out_size, void* d_ws, size_t ws_size,
                              hipStream_t stream) {
  const float* latent = (const float*)d_in[0];   // [4,256,32,32]
  const float* cb     = (const float*)d_in[1];   // [16384,256]
  const float* dec_w  = (const float*)d_in[2];   // [3,256,3,3]
  const float* dec_b  = (const float*)d_in[3];   // [3]
  float* out = (float*)d_out;                    // [4,3,32,32]

  char* ws = (char*)d_ws;
  u64*   partial = (u64*)ws;                          // 4096*128*8 = 4 MB
  float* cnorm   = (float*)(ws + 4194304);            // 64 KB
  int*   idx     = (int*)  (ws + 4259840);            // 16 KB
  float* wt      = (float*)(ws + 4276224);            // 27 KB

  k_cnorm<<<dim3(N_CODE / 4), dim3(256), 0, stream>>>(cb, cnorm);
  k_wt<<<dim3(27), dim3(256), 0, stream>>>(dec_w, wt);
  k_vq<<<dim3(NBLK, P_TOT / MT), dim3(256), 0, stream>>>(latent, cb, cnorm, partial);
  k_reduce<<<dim3(P_TOT), dim3(128), 0, stream>>>(partial, latent, cb, idx);
  k_conv<<<dim3(32, 4), dim3(256), 0, stream>>>(cb, idx, wt, dec_b, out);
}

// Round 2
// 231.812 us; speedup vs baseline: 2.4429x; 2.4429x over previous
//
#include <hip/hip_runtime.h>
#include <hip/hip_bf16.h>
#include <stdint.h>

#define P_TOT   4096
#define N_CODE  16384
#define DIM     256
#define HW      1024
#define CHW     262144
#define BM      128
#define BN      128
#define BK      32
#define NBLK    128

typedef unsigned long long u64;
typedef unsigned short u16;
typedef __attribute__((ext_vector_type(4))) float f32x4;
typedef __attribute__((ext_vector_type(8))) short bf16x8;

__device__ __forceinline__ unsigned int mono(float f) {
  unsigned int u = __float_as_uint(f);
  return (u & 0x80000000u) ? ~u : (u | 0x80000000u);
}
__device__ __forceinline__ u16 f2bf(float f) {
  __hip_bfloat16 h = __float2bfloat16(f);
  return *(u16*)&h;
}
__device__ __forceinline__ float bf2f(u16 b) {
  __hip_bfloat16 h = *(__hip_bfloat16*)&b;
  return __bfloat162float(h);
}
__device__ __forceinline__ void gload16(const void* g, void* l) {
  __builtin_amdgcn_global_load_lds(
      (const __attribute__((address_space(1))) unsigned int*)g,
      (__attribute__((address_space(3))) unsigned int*)l, 16, 0, 0);
}

// ---- split codebook into bf16 hi/lo: [16384][256] ----
__global__ __launch_bounds__(256) void k_split_cb(const float* __restrict__ src,
                                                  u16* __restrict__ hi,
                                                  u16* __restrict__ lo) {
  int i = blockIdx.x * 256 + threadIdx.x;     // 4096*256 threads, 4 floats each
  float4 v = ((const float4*)src)[i];
  ushort4 h, l;
  h.x = f2bf(v.x); l.x = f2bf(v.x - bf2f(h.x));
  h.y = f2bf(v.y); l.y = f2bf(v.y - bf2f(h.y));
  h.z = f2bf(v.z); l.z = f2bf(v.z - bf2f(h.z));
  h.w = f2bf(v.w); l.w = f2bf(v.w - bf2f(h.w));
  ((ushort4*)hi)[i] = h;
  ((ushort4*)lo)[i] = l;
}

// ---- transpose NCHW latent -> X[4096][256] + split into bf16 hi/lo ----
__global__ __launch_bounds__(256) void k_split_x(const float* __restrict__ latent,
                                                 u16* __restrict__ xhi,
                                                 u16* __restrict__ xlo) {
  __shared__ float ls[DIM][33];               // 32 pixels + pad
  int b = blockIdx.x >> 5;
  int hw0 = (blockIdx.x & 31) * 32;
  int t = threadIdx.x;
  int pixL = t & 31, cgL = t >> 5;            // load mapping: 8 channels x 32 pix
  for (int cq = 0; cq < 32; cq++) {
    int c = cq * 8 + cgL;
    ls[c][pixL] = latent[(size_t)b * CHW + (size_t)c * HW + hw0 + pixL];
  }
  __syncthreads();
  int pix = t >> 3, cg = t & 7;               // store mapping: 32 pix x 8 groups
  size_t p = (size_t)(b * HW + hw0 + pix);
  #pragma unroll
  for (int q = 0; q < 8; q++) {
    int c0 = cg * 32 + q * 4;
    ushort4 h, l;
    float v0 = ls[c0 + 0][pix], v1 = ls[c0 + 1][pix];
    float v2 = ls[c0 + 2][pix], v3 = ls[c0 + 3][pix];
    h.x = f2bf(v0); l.x = f2bf(v0 - bf2f(h.x));
    h.y = f2bf(v1); l.y = f2bf(v1 - bf2f(h.y));
    h.z = f2bf(v2); l.z = f2bf(v2 - bf2f(h.z));
    h.w = f2bf(v3); l.w = f2bf(v3 - bf2f(h.w));
    *(ushort4*)&xhi[p * DIM + c0] = h;
    *(ushort4*)&xlo[p * DIM + c0] = l;
  }
}

// ---- codebook squared norms (fp32 exact path) ----
__global__ __launch_bounds__(256) void k_cnorm(const float* __restrict__ cb,
                                               float* __restrict__ cnorm) {
  int code = blockIdx.x * 4 + (threadIdx.x >> 6);
  int lane = threadIdx.x & 63;
  float4 v = ((const float4*)(cb + (size_t)code * DIM))[lane];
  float s = fmaf(v.x, v.x, fmaf(v.y, v.y, fmaf(v.z, v.z, v.w * v.w)));
  #pragma unroll
  for (int off = 32; off; off >>= 1) s += __shfl_down(s, off, 64);
  if (lane == 0) cnorm[code] = s;
}

// ---- transpose dec_w [3][256][3][3] -> [oc][ky][kx][256] ----
__global__ __launch_bounds__(256) void k_wt(const float* __restrict__ w,
                                            float* __restrict__ wt) {
  int e = blockIdx.x * 256 + threadIdx.x;
  int ic = e & 255;
  int r = e >> 8;
  int kx = r % 3; r /= 3;
  int ky = r % 3;
  int oc = r / 3;
  wt[e] = w[((oc * 256 + ic) * 3 + ky) * 3 + kx];
}

// ---- main VQ: split-bf16 MFMA distance + fused argmin partial ----
__global__ __launch_bounds__(256) void k_vq(const u16* __restrict__ xhi,
                                            const u16* __restrict__ xlo,
                                            const u16* __restrict__ chi,
                                            const u16* __restrict__ clo,
                                            const float* __restrict__ cnorm,
                                            u64* __restrict__ partial) {
  __shared__ __align__(16) u16 xs_hi[BM * BK];
  __shared__ __align__(16) u16 xs_lo[BM * BK];
  __shared__ __align__(16) u16 cs_hi[BN * BK];
  __shared__ __align__(16) u16 cs_lo[BN * BK];
  __shared__ float cn[BN];
  __shared__ u64 red[BM][2];

  int nb = blockIdx.x, mb = blockIdx.y;
  int t = threadIdx.x;
  int lane = t & 63, w = t >> 6;
  int wr = w >> 1, wc = w & 1;                // 2x2 wave grid, 64x64 each
  int fr = lane & 15, fk = (lane >> 4) * 8;

  if (t < BN) cn[t] = cnorm[nb * BN + t];

  f32x4 acc[4][4] = {};

  int srow = t >> 2;                          // staging: 4 threads/row
  int scol = (t & 3) * 8;
  const u16* Xh = xhi + (size_t)mb * BM * DIM;
  const u16* Xl = xlo + (size_t)mb * BM * DIM;
  const u16* Ch = chi + (size_t)nb * BN * DIM;
  const u16* Cl = clo + (size_t)nb * BN * DIM;
  int lofs = t * 8;                           // elements (x2B = 16B/thread)

  for (int kb = 0; kb < DIM; kb += BK) {
    __syncthreads();
    #pragma unroll
    for (int h = 0; h < 2; h++) {
      size_t goff = (size_t)(h * 64 + srow) * DIM + kb + scol;
      int dst = h * 2048 + lofs;
      gload16(Xh + goff, &xs_hi[dst]);
      gload16(Xl + goff, &xs_lo[dst]);
      gload16(Ch + goff, &cs_hi[dst]);
      gload16(Cl + goff, &cs_lo[dst]);
    }
    __syncthreads();
    bf16x8 ah[4], al[4], bh[4], bl[4];
    #pragma unroll
    for (int i = 0; i < 4; i++) {
      int r = wr * 64 + i * 16 + fr;
      ah[i] = *(const bf16x8*)&xs_hi[r * BK + fk];
      al[i] = *(const bf16x8*)&xs_lo[r * BK + fk];
    }
    #pragma unroll
    for (int j = 0; j < 4; j++) {
      int c = wc * 64 + j * 16 + fr;
      bh[j] = *(const bf16x8*)&cs_hi[c * BK + fk];
      bl[j] = *(const bf16x8*)&cs_lo[c * BK + fk];
    }
    #pragma unroll
    for (int i = 0; i < 4; i++)
      #pragma unroll
      for (int j = 0; j < 4; j++) {
        acc[i][j] = __builtin_amdgcn_mfma_f32_16x16x32_bf16(ah[i], bh[j], acc[i][j], 0, 0, 0);
        acc[i][j] = __builtin_amdgcn_mfma_f32_16x16x32_bf16(ah[i], bl[j], acc[i][j], 0, 0, 0);
        acc[i][j] = __builtin_amdgcn_mfma_f32_16x16x32_bf16(al[i], bh[j], acc[i][j], 0, 0, 0);
      }
  }

  // ---- fused argmin epilogue ----
  int frow = lane >> 4;
  #pragma unroll
  for (int i = 0; i < 4; i++) {
    u64 best[4];
    #pragma unroll
    for (int r = 0; r < 4; r++) best[r] = ~0ull;
    #pragma unroll
    for (int j = 0; j < 4; j++) {
      int cloc = wc * 64 + j * 16 + fr;
      float cnj = cn[cloc];
      unsigned gcode = (unsigned)(nb * BN + cloc);
      #pragma unroll
      for (int r = 0; r < 4; r++) {
        float val = fmaf(-2.0f, acc[i][j][r], cnj);   // ||c||^2 - 2 x.c
        u64 key = ((u64)mono(val) << 32) | gcode;
        if (key < best[r]) best[r] = key;
      }
    }
    #pragma unroll
    for (int d = 1; d < 16; d <<= 1) {
      #pragma unroll
      for (int r = 0; r < 4; r++) {
        u64 o = __shfl_xor(best[r], d, 64);
        if (o < best[r]) best[r] = o;
      }
    }
    if (fr == 0) {
      int rbase = wr * 64 + i * 16 + frow * 4;
      #pragma unroll
      for (int r = 0; r < 4; r++) red[rbase + r][wc] = best[r];
    }
  }
  __syncthreads();
  if (t < BM) {
    u64 a = red[t][0], b = red[t][1];
    partial[(size_t)(mb * BM + t) * NBLK + nb] = a < b ? a : b;
  }
}

// ---- per-row top-2 reduce + exact fp64 refinement -> final index ----
__global__ __launch_bounds__(128) void k_reduce(const u64* __restrict__ partial,
                                                const float* __restrict__ latent,
                                                const float* __restrict__ cb,
                                                int* __restrict__ idxo) {
  int p = blockIdx.x;
  int t = threadIdx.x;
  __shared__ u64 s[128];
  u64 v = partial[(size_t)p * NBLK + t];
  s[t] = v; __syncthreads();
  #pragma unroll
  for (int off = 64; off; off >>= 1) {
    if (t < off) { u64 o = s[t + off]; if (o < s[t]) s[t] = o; }
    __syncthreads();
  }
  u64 m1 = s[0]; __syncthreads();
  s[t] = (v == m1) ? 0xFFFFFFFFFFFFFFFFull : v; __syncthreads();
  #pragma unroll
  for (int off = 64; off; off >>= 1) {
    if (t < off) { u64 o = s[t + off]; if (o < s[t]) s[t] = o; }
    __syncthreads();
  }
  u64 m2 = s[0];
  int n1 = (int)(m1 & 0xFFFFFFFFull);
  int n2 = (int)(m2 & 0xFFFFFFFFull);

  int b = p >> 10, hw = p & 1023;
  const float* xb = latent + (size_t)b * CHW + hw;
  double d1 = 0.0, d2 = 0.0;
  for (int c = t; c < DIM; c += 128) {
    double xv = (double)xb[(size_t)c * HW];
    double e1 = xv - (double)cb[(size_t)n1 * DIM + c]; d1 += e1 * e1;
    double e2 = xv - (double)cb[(size_t)n2 * DIM + c]; d2 += e2 * e2;
  }
  __shared__ double r1[128], r2[128];
  r1[t] = d1; r2[t] = d2; __syncthreads();
  #pragma unroll
  for (int off = 64; off; off >>= 1) {
    if (t < off) { r1[t] += r1[t + off]; r2[t] += r2[t + off]; }
    __syncthreads();
  }
  if (t == 0) {
    int best = (r2[0] < r1[0] || (r2[0] == r1[0] && n2 < n1)) ? n2 : n1;
    idxo[p] = best;
  }
}

// ---- gather + 3x3 conv + bias + (x+1)*0.5 + clamp ----
__global__ __launch_bounds__(256) void k_conv(const float* __restrict__ cb,
                                              const int* __restrict__ idx,
                                              const float* __restrict__ wt,
                                              const float* __restrict__ bias,
                                              float* __restrict__ out) {
  int y = blockIdx.x, b = blockIdx.y;
  int t = threadIdx.x;
  int x = t & 31, icg = t >> 5;
  float a0 = 0.f, a1 = 0.f, a2 = 0.f;
  #pragma unroll
  for (int dy = -1; dy <= 1; dy++) {
    int yy = y + dy;
    if (yy < 0 || yy >= 32) continue;
    #pragma unroll
    for (int dx = -1; dx <= 1; dx++) {
      int xx = x + dx;
      if (xx < 0 || xx >= 32) continue;
      int n = idx[b * HW + yy * 32 + xx];
      const float4* crow = (const float4*)(cb + (size_t)n * DIM + icg * 32);
      int tap = (dy + 1) * 3 + (dx + 1);
      const float4* w0 = (const float4*)(wt + (size_t)(0 * 9 + tap) * DIM + icg * 32);
      const float4* w1 = (const float4*)(wt + (size_t)(1 * 9 + tap) * DIM + icg * 32);
      const float4* w2 = (const float4*)(wt + (size_t)(2 * 9 + tap) * DIM + icg * 32);
      #pragma unroll
      for (int q = 0; q < 8; q++) {
        float4 qv = crow[q];
        float4 wa = w0[q];
        a0 = fmaf(qv.x, wa.x, a0); a0 = fmaf(qv.y, wa.y, a0);
        a0 = fmaf(qv.z, wa.z, a0); a0 = fmaf(qv.w, wa.w, a0);
        float4 wb = w1[q];
        a1 = fmaf(qv.x, wb.x, a1); a1 = fmaf(qv.y, wb.y, a1);
        a1 = fmaf(qv.z, wb.z, a1); a1 = fmaf(qv.w, wb.w, a1);
        float4 wcv = w2[q];
        a2 = fmaf(qv.x, wcv.x, a2); a2 = fmaf(qv.y, wcv.y, a2);
        a2 = fmaf(qv.z, wcv.z, a2); a2 = fmaf(qv.w, wcv.w, a2);
      }
    }
  }
  __shared__ float red[3][32][8];
  red[0][x][icg] = a0; red[1][x][icg] = a1; red[2][x][icg] = a2;
  __syncthreads();
  if (t < 96) {
    int oc = t >> 5, xo = t & 31;
    float sum = 0.f;
    #pragma unroll
    for (int k = 0; k < 8; k++) sum += red[oc][xo][k];
    sum += bias[oc];
    sum = (sum + 1.0f) * 0.5f;
    sum = fminf(fmaxf(sum, 0.0f), 1.0f);
    out[((size_t)(b * 3 + oc) * 32 + y) * 32 + xo] = sum;
  }
}

extern "C" void kernel_launch(void* const* d_in, const int* in_sizes, int n_in,
                              void* d_out, int out_size, void* d_ws, size_t ws_size,
                              hipStream_t stream) {
  const float* latent = (const float*)d_in[0];   // [4,256,32,32]
  const float* cb     = (const float*)d_in[1];   // [16384,256]
  const float* dec_w  = (const float*)d_in[2];   // [3,256,3,3]
  const float* dec_b  = (const float*)d_in[3];   // [3]
  float* out = (float*)d_out;                    // [4,3,32,32]

  char* ws = (char*)d_ws;
  u64*   partial = (u64*)ws;                          // 4 MB
  float* cnorm   = (float*)(ws + 4194304);            // 64 KB
  int*   idx     = (int*)  (ws + 4259840);            // 16 KB
  float* wt      = (float*)(ws + 4276224);            // 27 KB
  u16*   xhi     = (u16*)  (ws + 8388608);            // 2 MB
  u16*   xlo     = (u16*)  (ws + 10485760);           // 2 MB
  u16*   chi     = (u16*)  (ws + 12582912);           // 8 MB
  u16*   clo     = (u16*)  (ws + 20971520);           // 8 MB  (ends at 28 MB)

  k_split_cb<<<dim3(4096), dim3(256), 0, stream>>>(cb, chi, clo);
  k_split_x <<<dim3(128), dim3(256), 0, stream>>>(latent, xhi, xlo);
  k_cnorm   <<<dim3(N_CODE / 4), dim3(256), 0, stream>>>(cb, cnorm);
  k_wt      <<<dim3(27), dim3(256), 0, stream>>>(dec_w, wt);
  k_vq      <<<dim3(NBLK, P_TOT / BM), dim3(256), 0, stream>>>(xhi, xlo, chi, clo, cnorm, partial);
  k_reduce  <<<dim3(P_TOT), dim3(128), 0, stream>>>(partial, latent, cb, idx);
  k_conv    <<<dim3(32, 4), dim3(256), 0, stream>>>(cb, idx, wt, dec_b, out);
}

// Round 5
// 203.698 us; speedup vs baseline: 2.7801x; 1.1380x over previous
//
#include <hip/hip_runtime.h>
#include <hip/hip_bf16.h>
#include <stdint.h>

#define P_TOT   4096
#define N_CODE  16384
#define DIM     256
#define HW      1024
#define CHW     262144
#define NBLK    64        // 16384 / 256

typedef unsigned long long u64;
typedef unsigned short u16;
typedef __attribute__((ext_vector_type(4))) float f32x4;
typedef __attribute__((ext_vector_type(8))) short bf16x8;
typedef __attribute__((ext_vector_type(8))) unsigned short ushort8;

#define FENCE() asm volatile("" ::: "memory")
#define BAR()   __builtin_amdgcn_s_barrier()
#define VM(n)   asm volatile("s_waitcnt vmcnt(" #n ")" ::: "memory")

__device__ __forceinline__ unsigned int mono(float f) {
  unsigned int u = __float_as_uint(f);
  return (u & 0x80000000u) ? ~u : (u | 0x80000000u);
}
__device__ __forceinline__ u16 f2bf(float f) {
  __hip_bfloat16 h = __float2bfloat16(f);
  return *(u16*)&h;
}
__device__ __forceinline__ float bf2f(u16 b) {
  __hip_bfloat16 h = *(__hip_bfloat16*)&b;
  return __bfloat162float(h);
}
__device__ __forceinline__ void gload16(const void* g, void* l) {
  __builtin_amdgcn_global_load_lds(
      (const __attribute__((address_space(1))) unsigned int*)g,
      (__attribute__((address_space(3))) unsigned int*)l, 16, 0, 0);
}

// ---- codebook -> fragment-linear bf16 hi/lo:
// bfrag unit = [nb*8+kt)*4+bq] of 4096 u16: [h(2)][s(4)][row64][8elem]
__global__ __launch_bounds__(256) void k_split_cb(const float* __restrict__ cb,
                                                  u16* __restrict__ bfrag) {
  __shared__ float ls[64][68];
  int blk = blockIdx.x;            // 1024 = nb(64) x bq(4) x kp(4)
  int kp = blk & 3, bq = (blk >> 2) & 3, nb = blk >> 4;
  int t = threadIdx.x;
  int code0 = nb * 256 + bq * 64;
  int k0 = kp * 64;
  int lr = t >> 4, lc = (t & 15) * 4;
  #pragma unroll
  for (int pss = 0; pss < 4; ++pss) {
    int row = pss * 16 + lr;
    float4 v = *(const float4*)&cb[(size_t)(code0 + row) * DIM + k0 + lc];
    ls[row][lc] = v.x; ls[row][lc + 1] = v.y; ls[row][lc + 2] = v.z; ls[row][lc + 3] = v.w;
  }
  __syncthreads();
  int row64 = t & 63, g = t >> 6;
  #pragma unroll
  for (int it = 0; it < 4; ++it) {
    int combo = it * 4 + g;        // kt2*8 + s*2 + h
    int kt2 = combo >> 3, s = (combo >> 1) & 3, h = combo & 1;
    int kt = kp * 2 + kt2;
    ushort8 o;
    #pragma unroll
    for (int e = 0; e < 8; ++e) {
      float x = ls[row64][kt2 * 32 + s * 8 + e];
      u16 hi = f2bf(x);
      o[e] = h ? f2bf(x - bf2f(hi)) : hi;
    }
    size_t unitIdx = (size_t)(nb * 8 + kt) * 4 + bq;
    *(ushort8*)&bfrag[unitIdx * 4096 + (size_t)((h * 4 + s) * 64 + row64) * 8] = o;
  }
}

// ---- latent NCHW -> fragment-linear bf16 hi/lo X
__global__ __launch_bounds__(256) void k_split_x(const float* __restrict__ latent,
                                                 u16* __restrict__ xfrag) {
  __shared__ float ls[256][68];
  int blk = blockIdx.x;            // 64 = mb(16) x aq(4)
  int aq = blk & 3, mb = blk >> 2;
  int t = threadIdx.x;
  int gp0 = mb * 256 + aq * 64;
  int b = gp0 >> 10, hw0 = gp0 & 1023;
  int hw = t & 63, cg = t >> 6;
  for (int pss = 0; pss < 64; ++pss) {
    int c = pss * 4 + cg;
    ls[c][hw] = latent[(size_t)b * CHW + (size_t)c * HW + hw0 + hw];
  }
  __syncthreads();
  int row64 = t & 63, g = t >> 6;
  #pragma unroll
  for (int it = 0; it < 16; ++it) {
    int combo = it * 4 + g;        // kt*8 + s*2 + h
    int kt = combo >> 3, s = (combo >> 1) & 3, h = combo & 1;
    ushort8 o;
    #pragma unroll
    for (int e = 0; e < 8; ++e) {
      float x = ls[kt * 32 + s * 8 + e][row64];
      u16 hi = f2bf(x);
      o[e] = h ? f2bf(x - bf2f(hi)) : hi;
    }
    size_t unitIdx = (size_t)(mb * 8 + kt) * 4 + aq;
    *(ushort8*)&xfrag[unitIdx * 4096 + (size_t)((h * 4 + s) * 64 + row64) * 8] = o;
  }
}

// ---- codebook squared norms (fp32 exact) ----
__global__ __launch_bounds__(256) void k_cnorm(const float* __restrict__ cb,
                                               float* __restrict__ cnorm) {
  int code = blockIdx.x * 4 + (threadIdx.x >> 6);
  int lane = threadIdx.x & 63;
  float4 v = ((const float4*)(cb + (size_t)code * DIM))[lane];
  float s = fmaf(v.x, v.x, fmaf(v.y, v.y, fmaf(v.z, v.z, v.w * v.w)));
  #pragma unroll
  for (int off = 32; off; off >>= 1) s += __shfl_down(s, off, 64);
  if (lane == 0) cnorm[code] = s;
}

// ---- transpose dec_w [3][256][3][3] -> [oc][ky][kx][256] ----
__global__ __launch_bounds__(256) void k_wt(const float* __restrict__ w,
                                            float* __restrict__ wt) {
  int e = blockIdx.x * 256 + threadIdx.x;
  int ic = e & 255;
  int r = e >> 8;
  int kx = r % 3; r /= 3;
  int ky = r % 3;
  int oc = r / 3;
  wt[e] = w[((oc * 256 + ic) * 3 + ky) * 3 + kx];
}

// ================== main VQ: 256x256 8-phase counted-vmcnt ==================
__global__ __launch_bounds__(512, 2) void k_vq(const u16* __restrict__ xfrag,
                                               const u16* __restrict__ bfrag,
                                               const float* __restrict__ cnorm,
                                               u64* __restrict__ partial) {
  __shared__ u16 lds[2][2][4][4096];   // [buf][A/B][unit][8KB] = 128 KiB

  // XCD-chunked swizzle: 1024 wgs, 128 per XCD -> 8 nb-panels private per XCD
  int bid = blockIdx.x;
  int wg = (bid & 7) * 128 + (bid >> 3);
  int nb = wg >> 4;        // 0..63
  int mb = wg & 15;        // 0..15

  int tid = threadIdx.x;
  int lane = tid & 63, w = tid >> 6;
  int fr = lane & 15, s = lane >> 4;
  int aq = w >> 1;
  int rbase = (w & 1) * 32;            // row_local base within A-quarter
  int tid8 = tid * 8;                  // u16 elems = 16B/thread

  const u16* Xb = xfrag + (size_t)mb * 32 * 4096;   // [kt][aq] units
  const u16* Bb = bfrag + (size_t)nb * 32 * 4096;   // [kt][bq] units

  f32x4 acc[2][16] = {};
  bf16x8 ah[2], al[2], bh[4], bl[4];

  // ---- prologue: stage tile 0 (units A0..A3, B0..B3) into buf0 ----
  #pragma unroll
  for (int r = 0; r < 4; ++r) gload16(Xb + (size_t)r * 4096 + tid8, &lds[0][0][r][0] + tid8);
  #pragma unroll
  for (int r = 0; r < 4; ++r) gload16(Bb + (size_t)r * 4096 + tid8, &lds[0][1][r][0] + tid8);
  VM(3);                               // A0..A3 + B0 done; B1,B2,B3 in flight
  BAR(); FENCE();

  #define READ_A(LA)                                                          \
    _Pragma("unroll")                                                         \
    for (int m = 0; m < 2; ++m) {                                             \
      ah[m] = *(const bf16x8*)&(LA)[aq * 4096 + (size_t)((0 + s) * 64 + rbase + m * 16 + fr) * 8]; \
      al[m] = *(const bf16x8*)&(LA)[aq * 4096 + (size_t)((4 + s) * 64 + rbase + m * 16 + fr) * 8]; \
    }
  #define READ_B(LB, q)                                                       \
    _Pragma("unroll")                                                         \
    for (int j = 0; j < 4; ++j) {                                             \
      bh[j] = *(const bf16x8*)&(LB)[(q) * 4096 + (size_t)((0 + s) * 64 + j * 16 + fr) * 8]; \
      bl[j] = *(const bf16x8*)&(LB)[(q) * 4096 + (size_t)((4 + s) * 64 + j * 16 + fr) * 8]; \
    }
  #define MFMAQ(q)                                                            \
    __builtin_amdgcn_s_setprio(1);                                            \
    _Pragma("unroll")                                                         \
    for (int m = 0; m < 2; ++m) {                                             \
      _Pragma("unroll")                                                       \
      for (int j = 0; j < 4; ++j)                                             \
        acc[m][(q) * 4 + j] = __builtin_amdgcn_mfma_f32_16x16x32_bf16(ah[m], bh[j], acc[m][(q) * 4 + j], 0, 0, 0); \
    }                                                                         \
    _Pragma("unroll")                                                         \
    for (int m = 0; m < 2; ++m) {                                             \
      _Pragma("unroll")                                                       \
      for (int j = 0; j < 4; ++j)                                             \
        acc[m][(q) * 4 + j] = __builtin_amdgcn_mfma_f32_16x16x32_bf16(ah[m], bl[j], acc[m][(q) * 4 + j], 0, 0, 0); \
    }                                                                         \
    _Pragma("unroll")                                                         \
    for (int m = 0; m < 2; ++m) {                                             \
      _Pragma("unroll")                                                       \
      for (int j = 0; j < 4; ++j)                                             \
        acc[m][(q) * 4 + j] = __builtin_amdgcn_mfma_f32_16x16x32_bf16(al[m], bh[j], acc[m][(q) * 4 + j], 0, 0, 0); \
    }                                                                         \
    __builtin_amdgcn_s_setprio(0);

  // ---- main loop: tiles 0..6 (steady state, stage tile t+1) ----
  for (int t = 0; t < 7; ++t) {
    const int cur = t & 1, nxt = cur ^ 1;
    u16* LA = &lds[cur][0][0][0];
    u16* LB = &lds[cur][1][0][0];
    const size_t u1 = (size_t)(t + 1) * 4;
    // phase 0
    READ_A(LA); READ_B(LB, 0);
    gload16(Xb + (u1 + 0) * 4096 + tid8, &lds[nxt][0][0][0] + tid8);
    gload16(Xb + (u1 + 1) * 4096 + tid8, &lds[nxt][0][1][0] + tid8);
    BAR();
    MFMAQ(0);
    VM(4); BAR(); FENCE();
    // phase 1
    READ_B(LB, 1);
    gload16(Xb + (u1 + 2) * 4096 + tid8, &lds[nxt][0][2][0] + tid8);
    gload16(Xb + (u1 + 3) * 4096 + tid8, &lds[nxt][0][3][0] + tid8);
    BAR();
    MFMAQ(1);
    VM(5); BAR(); FENCE();
    // phase 2
    READ_B(LB, 2);
    gload16(Bb + (u1 + 0) * 4096 + tid8, &lds[nxt][1][0][0] + tid8);
    gload16(Bb + (u1 + 1) * 4096 + tid8, &lds[nxt][1][1][0] + tid8);
    BAR();
    MFMAQ(2);
    VM(6); BAR(); FENCE();
    // phase 3
    READ_B(LB, 3);
    gload16(Bb + (u1 + 2) * 4096 + tid8, &lds[nxt][1][2][0] + tid8);
    gload16(Bb + (u1 + 3) * 4096 + tid8, &lds[nxt][1][3][0] + tid8);
    BAR();
    MFMAQ(3);
    VM(3); BAR(); FENCE();
  }
  // ---- tail: tile 7, drain vmcnt 2->1->0 ----
  {
    u16* LA = &lds[1][0][0][0];
    u16* LB = &lds[1][1][0][0];
    READ_A(LA); READ_B(LB, 0);
    BAR(); MFMAQ(0); VM(2); BAR(); FENCE();
    READ_B(LB, 1);
    BAR(); MFMAQ(1); VM(1); BAR(); FENCE();
    READ_B(LB, 2);
    BAR(); MFMAQ(2); VM(0); BAR(); FENCE();
    READ_B(LB, 3);
    BAR(); MFMAQ(3);
  }

  // ---- fused argmin epilogue (no LDS; per-wave rows w*32..w*32+31) ----
  float cnr[16];
  #pragma unroll
  for (int n = 0; n < 16; ++n) cnr[n] = cnorm[nb * 256 + n * 16 + fr];

  #pragma unroll
  for (int m = 0; m < 2; ++m) {
    u64 best[4];
    #pragma unroll
    for (int r = 0; r < 4; ++r) best[r] = ~0ull;
    #pragma unroll
    for (int n = 0; n < 16; ++n) {
      unsigned code = (unsigned)(nb * 256 + n * 16 + fr);
      #pragma unroll
      for (int r = 0; r < 4; ++r) {
        float val = fmaf(-2.0f, acc[m][n][r], cnr[n]);
        u64 key = ((u64)mono(val) << 32) | code;
        if (key < best[r]) best[r] = key;
      }
    }
    #pragma unroll
    for (int d = 1; d < 16; d <<= 1) {
      #pragma unroll
      for (int r = 0; r < 4; ++r) {
        u64 o = __shfl_xor(best[r], d, 64);
        if (o < best[r]) best[r] = o;
      }
    }
    if (fr == 0) {
      int rowb = mb * 256 + w * 32 + m * 16 + s * 4;
      #pragma unroll
      for (int r = 0; r < 4; ++r)
        partial[(size_t)(rowb + r) * NBLK + nb] = best[r];
    }
  }
}

// ---- per-row top-2 reduce (1 wave) + exact fp64 refinement ----
__global__ __launch_bounds__(64) void k_reduce(const u64* __restrict__ partial,
                                               const float* __restrict__ latent,
                                               const float* __restrict__ cb,
                                               int* __restrict__ idxo) {
  int p = blockIdx.x;
  int t = threadIdx.x;
  u64 v = partial[(size_t)p * NBLK + t];
  u64 m1 = v;
  #pragma unroll
  for (int d = 1; d < 64; d <<= 1) { u64 o = __shfl_xor(m1, d, 64); if (o < m1) m1 = o; }
  u64 vv = (v == m1) ? ~0ull : v;
  u64 m2 = vv;
  #pragma unroll
  for (int d = 1; d < 64; d <<= 1) { u64 o = __shfl_xor(m2, d, 64); if (o < m2) m2 = o; }
  int n1 = (int)(m1 & 0xFFFFFFFFull);
  int n2 = (int)(m2 & 0xFFFFFFFFull);

  int b = p >> 10, hw = p & 1023;
  const float* xb = latent + (size_t)b * CHW + hw;
  double d1 = 0.0, d2 = 0.0;
  #pragma unroll
  for (int q = 0; q < 4; ++q) {
    int c = t * 4 + q;
    double xv = (double)xb[(size_t)c * HW];
    double e1 = xv - (double)cb[(size_t)n1 * DIM + c]; d1 += e1 * e1;
    double e2 = xv - (double)cb[(size_t)n2 * DIM + c]; d2 += e2 * e2;
  }
  #pragma unroll
  for (int d = 32; d; d >>= 1) {
    d1 += __shfl_down(d1, d, 64);
    d2 += __shfl_down(d2, d, 64);
  }
  if (t == 0) {
    idxo[p] = (d2 < d1 || (d2 == d1 && n2 < n1)) ? n2 : n1;
  }
}

// ---- gather + 3x3 conv + bias + (x+1)*0.5 + clamp ----
__global__ __launch_bounds__(256) void k_conv(const float* __restrict__ cb,
                                              const int* __restrict__ idx,
                                              const float* __restrict__ wt,
                                              const float* __restrict__ bias,
                                              float* __restrict__ out) {
  int y = blockIdx.x, b = blockIdx.y;
  int t = threadIdx.x;
  int x = t & 31, icg = t >> 5;
  float a0 = 0.f, a1 = 0.f, a2 = 0.f;
  #pragma unroll
  for (int dy = -1; dy <= 1; dy++) {
    int yy = y + dy;
    if (yy < 0 || yy >= 32) continue;
    #pragma unroll
    for (int dx = -1; dx <= 1; dx++) {
      int xx = x + dx;
      if (xx < 0 || xx >= 32) continue;
      int n = idx[b * HW + yy * 32 + xx];
      const float4* crow = (const float4*)(cb + (size_t)n * DIM + icg * 32);
      int tap = (dy + 1) * 3 + (dx + 1);
      const float4* w0 = (const float4*)(wt + (size_t)(0 * 9 + tap) * DIM + icg * 32);
      const float4* w1 = (const float4*)(wt + (size_t)(1 * 9 + tap) * DIM + icg * 32);
      const float4* w2 = (const float4*)(wt + (size_t)(2 * 9 + tap) * DIM + icg * 32);
      #pragma unroll
      for (int q = 0; q < 8; q++) {
        float4 qv = crow[q];
        float4 wa = w0[q];
        a0 = fmaf(qv.x, wa.x, a0); a0 = fmaf(qv.y, wa.y, a0);
        a0 = fmaf(qv.z, wa.z, a0); a0 = fmaf(qv.w, wa.w, a0);
        float4 wb = w1[q];
        a1 = fmaf(qv.x, wb.x, a1); a1 = fmaf(qv.y, wb.y, a1);
        a1 = fmaf(qv.z, wb.z, a1); a1 = fmaf(qv.w, wb.w, a1);
        float4 wcv = w2[q];
        a2 = fmaf(qv.x, wcv.x, a2); a2 = fmaf(qv.y, wcv.y, a2);
        a2 = fmaf(qv.z, wcv.z, a2); a2 = fmaf(qv.w, wcv.w, a2);
      }
    }
  }
  __shared__ float red[3][32][8];
  red[0][x][icg] = a0; red[1][x][icg] = a1; red[2][x][icg] = a2;
  __syncthreads();
  if (t < 96) {
    int oc = t >> 5, xo = t & 31;
    float sum = 0.f;
    #pragma unroll
    for (int k = 0; k < 8; k++) sum += red[oc][xo][k];
    sum += bias[oc];
    sum = (sum + 1.0f) * 0.5f;
    sum = fminf(fmaxf(sum, 0.0f), 1.0f);
    out[((size_t)(b * 3 + oc) * 32 + y) * 32 + xo] = sum;
  }
}

extern "C" void kernel_launch(void* const* d_in, const int* in_sizes, int n_in,
                              void* d_out, int out_size, void* d_ws, size_t ws_size,
                              hipStream_t stream) {
  const float* latent = (const float*)d_in[0];   // [4,256,32,32]
  const float* cb     = (const float*)d_in[1];   // [16384,256]
  const float* dec_w  = (const float*)d_in[2];   // [3,256,3,3]
  const float* dec_b  = (const float*)d_in[3];   // [3]
  float* out = (float*)d_out;                    // [4,3,32,32]

  char* ws = (char*)d_ws;
  u64*   partial = (u64*)ws;                      // 2 MB  [4096][64]
  float* cnorm   = (float*)(ws + 0x200000);       // 64 KB
  int*   idx     = (int*)  (ws + 0x210000);       // 16 KB
  float* wt      = (float*)(ws + 0x214000);       // 27 KB
  u16*   xfrag   = (u16*)  (ws + 0x400000);       // 4 MB
  u16*   bfrag   = (u16*)  (ws + 0x800000);       // 16 MB (ends at 24 MB)

  k_split_cb<<<dim3(1024), dim3(256), 0, stream>>>(cb, bfrag);
  k_split_x <<<dim3(64),   dim3(256), 0, stream>>>(latent, xfrag);
  k_cnorm   <<<dim3(N_CODE / 4), dim3(256), 0, stream>>>(cb, cnorm);
  k_wt      <<<dim3(27),   dim3(256), 0, stream>>>(dec_w, wt);
  k_vq      <<<dim3(1024), dim3(512), 0, stream>>>(xfrag, bfrag, cnorm, partial);
  k_reduce  <<<dim3(P_TOT), dim3(64), 0, stream>>>(partial, latent, cb, idx);
  k_conv    <<<dim3(32, 4), dim3(256), 0, stream>>>(cb, idx, wt, dec_b, out);
}